// Round 9
// baseline (182.579 us; speedup 1.0000x reference)
//
#include <hip/hip_runtime.h>
#include <hip/hip_bf16.h>

#define DD   4096   // hidden dim
#define NE   8      // experts
#define NR   16     // lora rank
#define NTOK 8192   // B*S
#define NDO  4096   // output dim
#define TAU  0.01f  // ambiguity margin for bf16 MFMA routing (err sigma ~1.2e-3)
#define MAXFLAG 8000
// SCALING = 16/16 = 1.0

typedef __attribute__((ext_vector_type(8))) __bf16 bf16x8;
typedef __attribute__((ext_vector_type(4))) __bf16 bf16x4;
typedef __attribute__((ext_vector_type(4))) float  f32x4;

__device__ __forceinline__ bf16x8 to_bf16x8(float4 a, float4 b) {
    bf16x8 r;
    r[0] = (__bf16)a.x; r[1] = (__bf16)a.y; r[2] = (__bf16)a.z; r[3] = (__bf16)a.w;
    r[4] = (__bf16)b.x; r[5] = (__bf16)b.y; r[6] = (__bf16)b.z; r[7] = (__bf16)b.w;
    return r;
}

// residual: lo = bf16(v - f32(hi))
__device__ __forceinline__ bf16x8 lo_bf16x8(float4 a, float4 b, bf16x8 h) {
    bf16x8 r;
    r[0] = (__bf16)(a.x - (float)h[0]); r[1] = (__bf16)(a.y - (float)h[1]);
    r[2] = (__bf16)(a.z - (float)h[2]); r[3] = (__bf16)(a.w - (float)h[3]);
    r[4] = (__bf16)(b.x - (float)h[4]); r[5] = (__bf16)(b.y - (float)h[5]);
    r[6] = (__bf16)(b.z - (float)h[6]); r[7] = (__bf16)(b.w - (float)h[7]);
    return r;
}

__device__ __forceinline__ bf16x8 zero_frag() {
    bf16x8 z;
    #pragma unroll
    for (int j = 0; j < 8; j++) z[j] = (__bf16)0.0f;
    return z;
}

// ---------------- k0: Bw f32 -> bf16 copy (one-time, 1 MB) ----------------
__global__ __launch_bounds__(256) void k_bw(const float* __restrict__ Bw,
                                            __bf16* __restrict__ Bwb) {
    const int i = (blockIdx.x * 256 + threadIdx.x) * 4;   // 512 blocks -> 524288 elems
    const float4 v = *(const float4*)(Bw + i);
    bf16x4 p;
    p[0] = (__bf16)v.x; p[1] = (__bf16)v.y; p[2] = (__bf16)v.z; p[3] = (__bf16)v.w;
    *(bf16x4*)(Bwb + i) = p;
}

// ---------------- k1: routing -- sequential x staging + bf16 MFMA ----------------
// 512 blocks x 1024 thr (16 waves). Block = 16 tokens. Per k-chunk of 1024:
// wave wv streams row wv of x SEQUENTIALLY (1KB/instr coalesced) into bf16 LDS
// tile, then computes its k-slice [wv*64,+64) via MFMA frags from LDS.
// B-frag rows 0-7 = bf16_hi(rw[e]), rows 8-15 = bf16_lo(rw[e]) ->
// logit[t][e] = sum over waves of (C[t][e] + C[t][e+8]). Residual = xl.w ~1.2e-3;
// tokens with top-2 gap < TAU go to exact f64 re-route (k_fix).
__global__ __launch_bounds__(1024) void k_route(const float* __restrict__ x,
                                                const float* __restrict__ rw,
                                                float* __restrict__ w_arr,
                                                int*   __restrict__ eid,
                                                int*   __restrict__ token_list,
                                                int*   __restrict__ count,
                                                int*   __restrict__ nflag,
                                                int*   __restrict__ flaglist) {
    const int t0   = blockIdx.x * 16;
    const int wv   = threadIdx.x >> 6;        // 0..15
    const int lane = threadIdx.x & 63;
    const int m    = lane & 15;
    const int half = lane >> 4;

    __shared__ __bf16 xt[16][1032];           // pad 8 bf16: row stride 516 dw (%32==4)
    __shared__ float  Lred[16][16][17];
    __shared__ float  logitS[16][NE];

    const float* xstage = x + (size_t)(t0 + wv) * DD;   // wave stages row wv
    const float* wrow   = rw + (size_t)(m & 7) * DD;
    const bool   blo    = m >= 8;

    f32x4 acc = {0.f, 0.f, 0.f, 0.f};

    for (int c = 0; c < 4; c++) {
        // ---- stage chunk c (sequential HBM reads, conflict-free b128 LDS writes)
        #pragma unroll
        for (int p = 0; p < 2; p++) {
            const int idx = p * 512 + lane * 8;
            const float4 va = *(const float4*)(xstage + c * 1024 + idx);
            const float4 vb = *(const float4*)(xstage + c * 1024 + idx + 4);
            *(bf16x8*)&xt[wv][idx] = to_bf16x8(va, vb);
        }
        __syncthreads();
        // ---- compute this wave's k-slice
        #pragma unroll
        for (int ks = 0; ks < 2; ks++) {
            const int kl = wv * 64 + ks * 32 + half * 8;   // LDS-local k
            const bf16x8 a = *(const bf16x8*)&xt[m][kl];
            const int kg = c * 1024 + kl;                  // global k
            const float4 wa = *(const float4*)(wrow + kg);
            const float4 wb = *(const float4*)(wrow + kg + 4);
            const bf16x8 bh = to_bf16x8(wa, wb);
            const bf16x8 b  = blo ? lo_bf16x8(wa, wb, bh) : bh;
            acc = __builtin_amdgcn_mfma_f32_16x16x32_bf16(a, b, acc, 0, 0, 0);
        }
        __syncthreads();   // protect tile before next stage overwrites
    }

    // C layout: row = (lane>>4)*4 + reg (token), col = lane&15 (e / e+8-lo)
    #pragma unroll
    for (int r = 0; r < 4; r++)
        Lred[wv][half * 4 + r][m] = acc[r];
    __syncthreads();

    if (threadIdx.x < 128) {
        const int t = threadIdx.x >> 3, ee = threadIdx.x & 7;
        float s = 0.f;
        #pragma unroll
        for (int w = 0; w < 16; w++) s += Lred[w][t][ee] + Lred[w][t][ee + 8];
        logitS[t][ee] = s;
    }
    __syncthreads();

    if (threadIdx.x < 16) {
        const int t = threadIdx.x;
        float best = -1e30f, second = -1e30f; int be = 0;
        #pragma unroll
        for (int e = 0; e < NE; e++) {
            const float s = logitS[t][e];
            if (s > best) { second = best; best = s; be = e; }
            else if (s > second) { second = s; }
        }
        const int tok = t0 + t;
        w_arr[tok] = best;
        if (best - second < TAU) {
            const int p = atomicAdd(nflag, 1);
            if (p < MAXFLAG) flaglist[p] = tok;
        } else {
            eid[tok] = be;
            const int p = atomicAdd(&count[be], 1);
            token_list[be * NTOK + p] = tok;
        }
    }
}

// ---------------- k1b: exact f64 re-route for ambiguous tokens ----------------
// 128 blocks x 256 thr; wave handles flagged tokens strided by 512.
__global__ __launch_bounds__(256) void k_fix(const float* __restrict__ x,
                                             const float* __restrict__ rw,
                                             float* __restrict__ w_arr,
                                             int*   __restrict__ eid,
                                             int*   __restrict__ token_list,
                                             int*   __restrict__ count,
                                             const int* __restrict__ nflag,
                                             const int* __restrict__ flaglist) {
    const int wv   = threadIdx.x >> 6;
    const int lane = threadIdx.x & 63;
    int n = *nflag; if (n > MAXFLAG) n = MAXFLAG;

    for (int idx = blockIdx.x * 4 + wv; idx < n; idx += 512) {
        const int tok = flaglist[idx];
        const float* xp = x + (size_t)tok * DD;
        double acc[NE];
        #pragma unroll
        for (int e = 0; e < NE; e++) acc[e] = 0.0;
        for (int i = 0; i < 16; i++) {
            const int d4 = (i * 64 + lane) * 4;
            const float4 xv = *(const float4*)(xp + d4);
            const double x0 = xv.x, x1 = xv.y, x2 = xv.z, x3 = xv.w;
            #pragma unroll
            for (int e = 0; e < NE; e++) {
                const float4 wv4 = *(const float4*)(rw + (size_t)e * DD + d4);
                acc[e] = fma(x0, (double)wv4.x, acc[e]);
                acc[e] = fma(x1, (double)wv4.y, acc[e]);
                acc[e] = fma(x2, (double)wv4.z, acc[e]);
                acc[e] = fma(x3, (double)wv4.w, acc[e]);
            }
        }
        #pragma unroll
        for (int off = 32; off > 0; off >>= 1)
            #pragma unroll
            for (int e = 0; e < NE; e++)
                acc[e] += __shfl_xor(acc[e], off, 64);
        if (lane == 0) {
            double best = acc[0]; int be = 0;
            #pragma unroll
            for (int e = 1; e < NE; e++) if (acc[e] > best) { best = acc[e]; be = e; }
            w_arr[tok] = (float)best;
            eid[tok] = be;
            const int pos = atomicAdd(&count[be], 1);
            token_list[be * NTOK + pos] = tok;
        }
    }
}

// ---------------- k2: wh[tok][r] = w * (x . A[e]^T)  (bf16 out) ----------------
// unchanged (proven ~18us; x is L3-hot after k_route): 32-token tile, 16 waves,
// wave = K-slice 256, 2 token-subtiles share one A B-frag.
__global__ __launch_bounds__(1024) void k_h(const float* __restrict__ x,
                                            const float* __restrict__ Am,
                                            const float* __restrict__ w_arr,
                                            const int*   __restrict__ token_list,
                                            const int*   __restrict__ count,
                                            __hip_bfloat16* __restrict__ wh) {
    const int e    = blockIdx.x >> 7;         // 8 experts x 128 slots
    const int g    = blockIdx.x & 127;
    const int cnt  = count[e];
    const int base = g * 32;
    if (base >= cnt) return;

    const int wv   = threadIdx.x >> 6;        // 0..15
    const int lane = threadIdx.x & 63;
    const int m    = lane & 15;
    const int half = lane >> 4;

    const int i0 = base + m,  i1 = base + 16 + m;
    const int tok0 = (i0 < cnt) ? token_list[e * NTOK + i0] : 0;
    const int tok1 = (i1 < cnt) ? token_list[e * NTOK + i1] : 0;
    const float* xr0  = x + (size_t)tok0 * DD;
    const float* xr1  = x + (size_t)tok1 * DD;
    const float* arow = Am + ((size_t)e * NR + m) * DD;

    f32x4 acc0 = {0.f,0.f,0.f,0.f}, acc1 = {0.f,0.f,0.f,0.f};
    const int kbase = wv * 256;
    #pragma unroll
    for (int kc = 0; kc < 8; kc++) {
        const int k0 = kbase + kc * 32 + half * 8;
        const bf16x8 bfrag = to_bf16x8(*(const float4*)(arow + k0),
                                       *(const float4*)(arow + k0 + 4));
        const bf16x8 a0 = to_bf16x8(*(const float4*)(xr0 + k0),
                                    *(const float4*)(xr0 + k0 + 4));
        const bf16x8 a1 = to_bf16x8(*(const float4*)(xr1 + k0),
                                    *(const float4*)(xr1 + k0 + 4));
        acc0 = __builtin_amdgcn_mfma_f32_16x16x32_bf16(a0, bfrag, acc0, 0, 0, 0);
        acc1 = __builtin_amdgcn_mfma_f32_16x16x32_bf16(a1, bfrag, acc1, 0, 0, 0);
    }

    __shared__ float lds[16][32][17];
    #pragma unroll
    for (int rr = 0; rr < 4; rr++) {
        lds[wv][half * 4 + rr][m]      = acc0[rr];
        lds[wv][16 + half * 4 + rr][m] = acc1[rr];
    }
    __syncthreads();

    if (threadIdx.x < 512) {
        const int t = threadIdx.x >> 4;
        const int r = threadIdx.x & 15;
        const int i2 = base + t;
        if (i2 < cnt) {
            float s = 0.f;
            #pragma unroll
            for (int w = 0; w < 16; w++) s += lds[w][t][r];
            const int tk = token_list[e * NTOK + i2];
            wh[(size_t)tk * NR + r] = (__hip_bfloat16)(s * w_arr[tk]);
        }
    }
}

// ---------------- k3: out = wh . Bw[e]^T, NATURAL token order ----------------
// 512 blocks x 512 thr (8 waves). Block = 64 consecutive tokens x 1024-o chunk
// (dense sequential writes). Expert handled by looping e=0..7 with per-lane
// masked A-frags accumulating into the same C (non-matching tokens add 0).
__global__ __launch_bounds__(512) void k_out(const __bf16* __restrict__ Bwb,
                                             const __hip_bfloat16* __restrict__ wh,
                                             const int* __restrict__ eid,
                                             float* __restrict__ out) {
    const int ochunk = blockIdx.x & 3;
    const int t0     = (blockIdx.x >> 2) * 64;
    const int wv     = threadIdx.x >> 6;      // 0..7
    const int lane   = threadIdx.x & 63;
    const int m      = lane & 15;
    const int half   = lane >> 4;
    const int h2     = (half < 2) ? half : 0;
    const bf16x8 zf  = zero_frag();

    // per-subtile A-frags (wh rows, K=32 zero-padded) + expert ids
    bf16x8 a2[4]; int es[4];
    #pragma unroll
    for (int s = 0; s < 4; s++) {
        const int tok = t0 + s * 16 + m;
        es[s] = eid[tok];
        a2[s] = (half < 2) ? *(const bf16x8*)((const __bf16*)wh + (size_t)tok * NR + half * 8)
                           : zf;
    }

    const int ob0 = ochunk * 1024 + wv * 128;
    #pragma unroll 2
    for (int ot = 0; ot < 8; ot++) {
        const int obase = ob0 + ot * 16;
        f32x4 acc0 = {0.f,0.f,0.f,0.f}, acc1 = {0.f,0.f,0.f,0.f};
        f32x4 acc2 = {0.f,0.f,0.f,0.f}, acc3 = {0.f,0.f,0.f,0.f};
        #pragma unroll
        for (int e = 0; e < NE; e++) {
            const bf16x8 b2 = (half < 2)
                ? *(const bf16x8*)(Bwb + ((size_t)e * NDO + obase + m) * NR + h2 * 8)
                : zf;
            acc0 = __builtin_amdgcn_mfma_f32_16x16x32_bf16(es[0] == e ? a2[0] : zf, b2, acc0, 0, 0, 0);
            acc1 = __builtin_amdgcn_mfma_f32_16x16x32_bf16(es[1] == e ? a2[1] : zf, b2, acc1, 0, 0, 0);
            acc2 = __builtin_amdgcn_mfma_f32_16x16x32_bf16(es[2] == e ? a2[2] : zf, b2, acc2, 0, 0, 0);
            acc3 = __builtin_amdgcn_mfma_f32_16x16x32_bf16(es[3] == e ? a2[3] : zf, b2, acc3, 0, 0, 0);
        }
        const int rbase = t0 + half * 4;
        #pragma unroll
        for (int r = 0; r < 4; r++) {
            out[(size_t)(rbase +  0 + r) * NDO + obase + m] = acc0[r];
            out[(size_t)(rbase + 16 + r) * NDO + obase + m] = acc1[r];
            out[(size_t)(rbase + 32 + r) * NDO + obase + m] = acc2[r];
            out[(size_t)(rbase + 48 + r) * NDO + obase + m] = acc3[r];
        }
    }
}

// ---------------- launcher ----------------
extern "C" void kernel_launch(void* const* d_in, const int* in_sizes, int n_in,
                              void* d_out, int out_size, void* d_ws, size_t ws_size,
                              hipStream_t stream) {
    const float* x  = (const float*)d_in[0];
    const float* rw = (const float*)d_in[1];
    const float* Am = (const float*)d_in[2];
    const float* Bw = (const float*)d_in[3];
    float* out = (float*)d_out;

    char* ws = (char*)d_ws;
    int*   count      = (int*)ws;                           // 8 ints @ 0
    int*   nflag      = (int*)(ws + 32);                    // 1 int
    float* w_arr      = (float*)(ws + 512);                 // 8192 f32 -> ends 33280
    int*   flaglist   = (int*)(ws + 33280);                 // 8064 ints -> ends 65536
    int*   token_list = (int*)(ws + 65536);                 // 8*8192 ints -> ends 327680
    __hip_bfloat16* wh = (__hip_bfloat16*)(ws + 327680);    // 8192*16 bf16 -> ends 589824
    int*   eid        = (int*)(ws + 589824);                // 8192 ints -> ends 622592
    __bf16* Bwb       = (__bf16*)(ws + 622592);             // 524288 bf16 -> ends 1671168

    hipMemsetAsync(ws, 0, 64, stream);                      // count + nflag
    hipLaunchKernelGGL(k_bw,    dim3(512),  dim3(256),  0, stream, Bw, Bwb);
    hipLaunchKernelGGL(k_route, dim3(512),  dim3(1024), 0, stream, x, rw, w_arr, eid, token_list, count, nflag, flaglist);
    hipLaunchKernelGGL(k_fix,   dim3(128),  dim3(256),  0, stream, x, rw, w_arr, eid, token_list, count, nflag, flaglist);
    hipLaunchKernelGGL(k_h,     dim3(1024), dim3(1024), 0, stream, x, Am, w_arr, token_list, count, wh);
    hipLaunchKernelGGL(k_out,   dim3(512),  dim3(512),  0, stream, Bwb, wh, eid, out);
}

// Round 10
// 171.989 us; speedup vs baseline: 1.0616x; 1.0616x over previous
//
#include <hip/hip_runtime.h>
#include <hip/hip_bf16.h>

#define DD   4096   // hidden dim
#define NE   8      // experts
#define NR   16     // lora rank
#define NTOK 8192   // B*S
#define NDO  4096   // output dim
#define TAU  0.01f  // ambiguity margin (bf16-x routing err sigma ~1.2e-3, r9-validated)
#define MAXFLAG 8000
// SCALING = 16/16 = 1.0

typedef __attribute__((ext_vector_type(8))) __bf16 bf16x8;
typedef __attribute__((ext_vector_type(4))) float  f32x4;

__device__ __forceinline__ bf16x8 to_bf16x8(float4 a, float4 b) {
    bf16x8 r;
    r[0] = (__bf16)a.x; r[1] = (__bf16)a.y; r[2] = (__bf16)a.z; r[3] = (__bf16)a.w;
    r[4] = (__bf16)b.x; r[5] = (__bf16)b.y; r[6] = (__bf16)b.z; r[7] = (__bf16)b.w;
    return r;
}

// residual: lo = bf16(v - f32(bf16(v)))
__device__ __forceinline__ bf16x8 lo_bf16x8(float4 a, float4 b, bf16x8 h) {
    bf16x8 r;
    r[0] = (__bf16)(a.x - (float)h[0]); r[1] = (__bf16)(a.y - (float)h[1]);
    r[2] = (__bf16)(a.z - (float)h[2]); r[3] = (__bf16)(a.w - (float)h[3]);
    r[4] = (__bf16)(b.x - (float)h[4]); r[5] = (__bf16)(b.y - (float)h[5]);
    r[6] = (__bf16)(b.z - (float)h[6]); r[7] = (__bf16)(b.w - (float)h[7]);
    return r;
}

__device__ __forceinline__ bf16x8 zero_frag() {
    bf16x8 z;
    #pragma unroll
    for (int j = 0; j < 8; j++) z[j] = (__bf16)0.0f;
    return z;
}

// ---------------- k_prep: barrier-free streaming bf16 compaction ----------------
// grid 4232 x 256 thr. Blocks 0..4095: xb = bf16(x) (8192 f32/block, 8 indep
// float4 loads per lane -> stores). 4096..4159: Ab. 4160..4223: Bwb.
// 4224..4231: rwhl rows 0-7 = hi(rw), rows 8-15 = lo(rw).
__global__ __launch_bounds__(256) void k_prep(const float* __restrict__ x,
                                              const float* __restrict__ rw,
                                              const float* __restrict__ Am,
                                              const float* __restrict__ Bw,
                                              __bf16* __restrict__ xb,
                                              __bf16* __restrict__ rwhl,
                                              __bf16* __restrict__ Ab,
                                              __bf16* __restrict__ Bwb) {
    const int b = blockIdx.x;
    const float* src;  __bf16* dst;  size_t base;
    if (b < 4096)      { base = (size_t)b * 8192 + threadIdx.x * 32;            src = x;  dst = xb;  }
    else if (b < 4160) { base = (size_t)(b - 4096) * 8192 + threadIdx.x * 32;   src = Am; dst = Ab;  }
    else if (b < 4224) { base = (size_t)(b - 4160) * 8192 + threadIdx.x * 32;   src = Bw; dst = Bwb; }
    else {
        // rwhl: 16 rows x 4096; row<8 -> hi, row>=8 -> lo of rw[row&7]
        const int obase = (b - 4224) * 8192 + threadIdx.x * 32;
        const int row = obase >> 12, k = obase & 4095;
        const float* s = rw + ((size_t)(row & 7) << 12) + k;
        float4 v[8];
        #pragma unroll
        for (int i = 0; i < 8; i++) v[i] = *(const float4*)(s + i * 4);
        if (row < 8) {
            #pragma unroll
            for (int i = 0; i < 4; i++)
                *(bf16x8*)(rwhl + obase + i * 8) = to_bf16x8(v[2*i], v[2*i+1]);
        } else {
            #pragma unroll
            for (int i = 0; i < 4; i++) {
                const bf16x8 h = to_bf16x8(v[2*i], v[2*i+1]);
                *(bf16x8*)(rwhl + obase + i * 8) = lo_bf16x8(v[2*i], v[2*i+1], h);
            }
        }
        return;
    }
    float4 v[8];
    #pragma unroll
    for (int i = 0; i < 8; i++) v[i] = *(const float4*)(src + base + i * 4);
    #pragma unroll
    for (int i = 0; i < 4; i++)
        *(bf16x8*)(dst + base + i * 8) = to_bf16x8(v[2*i], v[2*i+1]);
}

// ---------------- k1: routing via bf16 MFMA on L3-hot xb ----------------
// 512 blocks x 1024 thr (16 waves). Block = 16 tokens; wave = K-slice 256.
// A-frag: 16B load from xb row m. B-frag: 16B load from rwhl row m.
// logit[t][e] = sum over waves of (C[t][e](hi) + C[t][e+8](lo)).
__global__ __launch_bounds__(1024) void k_route(const __bf16* __restrict__ xb,
                                                const __bf16* __restrict__ rwhl,
                                                float* __restrict__ w_arr,
                                                int*   __restrict__ token_list,
                                                int*   __restrict__ count,
                                                int*   __restrict__ nflag,
                                                int*   __restrict__ flaglist) {
    const int t0   = blockIdx.x * 16;
    const int wv   = threadIdx.x >> 6;        // 0..15
    const int lane = threadIdx.x & 63;
    const int m    = lane & 15;
    const int half = lane >> 4;

    const __bf16* xrow = xb   + (size_t)(t0 + m) * DD;
    const __bf16* wrow = rwhl + (size_t)m * DD;

    f32x4 acc = {0.f, 0.f, 0.f, 0.f};
    const int kbase = wv * 256;
    #pragma unroll
    for (int ks = 0; ks < 8; ks++) {
        const int k0 = kbase + ks * 32 + half * 8;
        const bf16x8 a = *(const bf16x8*)(xrow + k0);
        const bf16x8 b = *(const bf16x8*)(wrow + k0);
        acc = __builtin_amdgcn_mfma_f32_16x16x32_bf16(a, b, acc, 0, 0, 0);
    }

    // C layout: row = (lane>>4)*4 + reg (token), col = lane&15 (B row)
    __shared__ float Lred[16][16][17];
    #pragma unroll
    for (int r = 0; r < 4; r++)
        Lred[wv][half * 4 + r][m] = acc[r];
    __syncthreads();

    __shared__ float logitS[16][NE];
    if (threadIdx.x < 128) {
        const int t = threadIdx.x >> 3, ee = threadIdx.x & 7;
        float s = 0.f;
        #pragma unroll
        for (int w = 0; w < 16; w++) s += Lred[w][t][ee] + Lred[w][t][ee + 8];
        logitS[t][ee] = s;
    }
    __syncthreads();

    if (threadIdx.x < 16) {
        const int t = threadIdx.x;
        float best = -1e30f, second = -1e30f; int be = 0;
        #pragma unroll
        for (int e = 0; e < NE; e++) {
            const float s = logitS[t][e];
            if (s > best) { second = best; best = s; be = e; }
            else if (s > second) { second = s; }
        }
        const int tok = t0 + t;
        w_arr[tok] = best;
        if (best - second < TAU) {
            const int p = atomicAdd(nflag, 1);
            if (p < MAXFLAG) flaglist[p] = tok;
        } else {
            const int p = atomicAdd(&count[be], 1);
            token_list[be * NTOK + p] = tok;
        }
    }
}

// ---------------- k1b: exact f64 re-route (original f32 data) ----------------
__global__ __launch_bounds__(256) void k_fix(const float* __restrict__ x,
                                             const float* __restrict__ rw,
                                             float* __restrict__ w_arr,
                                             int*   __restrict__ token_list,
                                             int*   __restrict__ count,
                                             const int* __restrict__ nflag,
                                             const int* __restrict__ flaglist) {
    const int wv   = threadIdx.x >> 6;
    const int lane = threadIdx.x & 63;
    int n = *nflag; if (n > MAXFLAG) n = MAXFLAG;

    for (int idx = blockIdx.x * 4 + wv; idx < n; idx += 512) {
        const int tok = flaglist[idx];
        const float* xp = x + (size_t)tok * DD;
        double acc[NE];
        #pragma unroll
        for (int e = 0; e < NE; e++) acc[e] = 0.0;
        for (int i = 0; i < 16; i++) {
            const int d4 = (i * 64 + lane) * 4;
            const float4 xv = *(const float4*)(xp + d4);
            const double x0 = xv.x, x1 = xv.y, x2 = xv.z, x3 = xv.w;
            #pragma unroll
            for (int e = 0; e < NE; e++) {
                const float4 wv4 = *(const float4*)(rw + (size_t)e * DD + d4);
                acc[e] = fma(x0, (double)wv4.x, acc[e]);
                acc[e] = fma(x1, (double)wv4.y, acc[e]);
                acc[e] = fma(x2, (double)wv4.z, acc[e]);
                acc[e] = fma(x3, (double)wv4.w, acc[e]);
            }
        }
        #pragma unroll
        for (int off = 32; off > 0; off >>= 1)
            #pragma unroll
            for (int e = 0; e < NE; e++)
                acc[e] += __shfl_xor(acc[e], off, 64);
        if (lane == 0) {
            double best = acc[0]; int be = 0;
            #pragma unroll
            for (int e = 1; e < NE; e++) if (acc[e] > best) { best = acc[e]; be = e; }
            w_arr[tok] = (float)best;
            const int pos = atomicAdd(&count[be], 1);
            token_list[be * NTOK + pos] = tok;
        }
    }
}

// ---------------- k2: wh[tok][r] = w * (xb . Ab[e]^T) ----------------
// r8-proven structure, now pure-bf16 frag loads (xb L3-hot, Ab L2).
__global__ __launch_bounds__(1024) void k_h(const __bf16* __restrict__ xb,
                                            const __bf16* __restrict__ Ab,
                                            const float* __restrict__ w_arr,
                                            const int*   __restrict__ token_list,
                                            const int*   __restrict__ count,
                                            __hip_bfloat16* __restrict__ wh) {
    const int e    = blockIdx.x >> 7;         // 8 experts x 128 slots
    const int g    = blockIdx.x & 127;
    const int cnt  = count[e];
    const int base = g * 32;
    if (base >= cnt) return;

    const int wv   = threadIdx.x >> 6;        // 0..15
    const int lane = threadIdx.x & 63;
    const int m    = lane & 15;
    const int half = lane >> 4;

    const int i0 = base + m,  i1 = base + 16 + m;
    const int tok0 = (i0 < cnt) ? token_list[e * NTOK + i0] : 0;
    const int tok1 = (i1 < cnt) ? token_list[e * NTOK + i1] : 0;
    const __bf16* xr0  = xb + (size_t)tok0 * DD;
    const __bf16* xr1  = xb + (size_t)tok1 * DD;
    const __bf16* arow = Ab + ((size_t)e * NR + m) * DD;

    f32x4 acc0 = {0.f,0.f,0.f,0.f}, acc1 = {0.f,0.f,0.f,0.f};
    const int kbase = wv * 256;
    #pragma unroll
    for (int kc = 0; kc < 8; kc++) {
        const int k0 = kbase + kc * 32 + half * 8;
        const bf16x8 bfrag = *(const bf16x8*)(arow + k0);
        const bf16x8 a0    = *(const bf16x8*)(xr0 + k0);
        const bf16x8 a1    = *(const bf16x8*)(xr1 + k0);
        acc0 = __builtin_amdgcn_mfma_f32_16x16x32_bf16(a0, bfrag, acc0, 0, 0, 0);
        acc1 = __builtin_amdgcn_mfma_f32_16x16x32_bf16(a1, bfrag, acc1, 0, 0, 0);
    }

    __shared__ float lds[16][32][17];
    #pragma unroll
    for (int rr = 0; rr < 4; rr++) {
        lds[wv][half * 4 + rr][m]      = acc0[rr];
        lds[wv][16 + half * 4 + rr][m] = acc1[rr];
    }
    __syncthreads();

    if (threadIdx.x < 512) {
        const int t = threadIdx.x >> 4;
        const int r = threadIdx.x & 15;
        const int i2 = base + t;
        if (i2 < cnt) {
            float s = 0.f;
            #pragma unroll
            for (int w = 0; w < 16; w++) s += lds[w][t][r];
            const int tk = token_list[e * NTOK + i2];
            wh[(size_t)tk * NR + r] = (__hip_bfloat16)(s * w_arr[tk]);
        }
    }
}

// ---------------- k3: out = wh . Bw[e]^T (r5-proven 37us config) ----------------
// grid 8e x 512slots x 4chunks = 16384 blocks of 256 thr (8192 live waves).
__global__ __launch_bounds__(256) void k_out(const __bf16* __restrict__ Bwb,
                                             const __hip_bfloat16* __restrict__ wh,
                                             const int*   __restrict__ token_list,
                                             const int*   __restrict__ count,
                                             float* __restrict__ out) {
    const int bx    = blockIdx.x;
    const int chunk = bx & 3;
    const int slot  = (bx >> 2) & 511;
    const int e     = bx >> 11;
    const int cnt   = count[e];
    const int base  = slot * 16;
    if (base >= cnt) return;

    const int wv   = threadIdx.x >> 6;        // 0..3
    const int lane = threadIdx.x & 63;
    const int m    = lane & 15;
    const int half = lane >> 4;

    const int  idx   = base + m;
    const bool valid = idx < cnt;
    const int  tok   = valid ? token_list[e * NTOK + idx] : 0;
    const bf16x8 zf  = zero_frag();

    bf16x8 a2 = (half < 2 && valid)
        ? *(const bf16x8*)((const __bf16*)wh + (size_t)tok * NR + half * 8)
        : zf;

    int trow[4]; bool vrow[4];
    #pragma unroll
    for (int r = 0; r < 4; r++) {
        const int ir = base + half * 4 + r;
        vrow[r] = ir < cnt;
        trow[r] = vrow[r] ? token_list[e * NTOK + ir] : 0;
    }

    const __bf16* bwe = Bwb + (size_t)e * NDO * NR;
    const int h2 = (half < 2) ? half : 0;
    const f32x4 zero4 = {0.f, 0.f, 0.f, 0.f};
    const int ob0 = chunk * 1024 + wv * 256;

    #pragma unroll 4
    for (int ot = 0; ot < 16; ot++) {
        const int obase = ob0 + ot * 16;
        const bf16x8 b2 = (half < 2)
            ? *(const bf16x8*)(bwe + (size_t)(obase + m) * NR + h2 * 8)
            : zf;
        const f32x4 d = __builtin_amdgcn_mfma_f32_16x16x32_bf16(a2, b2, zero4, 0, 0, 0);
        #pragma unroll
        for (int r = 0; r < 4; r++) {
            if (vrow[r]) out[(size_t)trow[r] * NDO + obase + m] = d[r];
        }
    }
}

// ---------------- launcher ----------------
extern "C" void kernel_launch(void* const* d_in, const int* in_sizes, int n_in,
                              void* d_out, int out_size, void* d_ws, size_t ws_size,
                              hipStream_t stream) {
    const float* x  = (const float*)d_in[0];
    const float* rw = (const float*)d_in[1];
    const float* Am = (const float*)d_in[2];
    const float* Bw = (const float*)d_in[3];
    float* out = (float*)d_out;

    char* ws = (char*)d_ws;
    int*   count      = (int*)ws;                           // 8 ints @ 0
    int*   nflag      = (int*)(ws + 32);                    // 1 int
    float* w_arr      = (float*)(ws + 512);                 // 8192 f32   -> ends 33280
    int*   flaglist   = (int*)(ws + 33280);                 // 8000 ints  -> ends 65280
    int*   token_list = (int*)(ws + 65536);                 // 64K ints   -> ends 327680
    __hip_bfloat16* wh = (__hip_bfloat16*)(ws + 327680);    // 128K bf16  -> ends 589824
    __bf16* rwhl      = (__bf16*)(ws + 589824);             // 64K bf16   -> ends 720896
    __bf16* Bwb       = (__bf16*)(ws + 720896);             // 512K bf16  -> ends 1769472
    __bf16* Ab        = (__bf16*)(ws + 1769472);            // 512K bf16  -> ends 2818048
    __bf16* xb        = (__bf16*)(ws + 4194304);            // 32M bf16   -> ends 71303168

    hipMemsetAsync(ws, 0, 64, stream);                      // count + nflag
    hipLaunchKernelGGL(k_prep,  dim3(4232),  dim3(256),  0, stream, x, rw, Am, Bw, xb, rwhl, Ab, Bwb);
    hipLaunchKernelGGL(k_route, dim3(512),   dim3(1024), 0, stream, xb, rwhl, w_arr, token_list, count, nflag, flaglist);
    hipLaunchKernelGGL(k_fix,   dim3(128),   dim3(256),  0, stream, x, rw, w_arr, token_list, count, nflag, flaglist);
    hipLaunchKernelGGL(k_h,     dim3(1024),  dim3(1024), 0, stream, xb, Ab, w_arr, token_list, count, wh);
    hipLaunchKernelGGL(k_out,   dim3(16384), dim3(256),  0, stream, Bwb, wh, token_list, count, out);
}

// Round 11
// 161.081 us; speedup vs baseline: 1.1335x; 1.0677x over previous
//
#include <hip/hip_runtime.h>
#include <hip/hip_bf16.h>

#define DD   4096   // hidden dim
#define NE   8      // experts
#define NR   16     // lora rank
#define NTOK 8192   // B*S
#define NDO  4096   // output dim
#define TAU  0.01f  // ambiguity margin (bf16-x routing err, r9/r10-validated)
#define MAXFLAG 8000
// SCALING = 16/16 = 1.0

typedef __attribute__((ext_vector_type(8))) __bf16 bf16x8;
typedef __attribute__((ext_vector_type(4))) __bf16 bf16x4;
typedef __attribute__((ext_vector_type(4))) float  f32x4;

__device__ __forceinline__ bf16x8 to_bf16x8(float4 a, float4 b) {
    bf16x8 r;
    r[0] = (__bf16)a.x; r[1] = (__bf16)a.y; r[2] = (__bf16)a.z; r[3] = (__bf16)a.w;
    r[4] = (__bf16)b.x; r[5] = (__bf16)b.y; r[6] = (__bf16)b.z; r[7] = (__bf16)b.w;
    return r;
}

__device__ __forceinline__ bf16x8 zero_frag() {
    bf16x8 z;
    #pragma unroll
    for (int j = 0; j < 8; j++) z[j] = (__bf16)0.0f;
    return z;
}

// ---------------- k_prep_w: weight conversions (tiny, ~2.2MB total) ----------------
// blocks 0..511: Bwb, 512..1023: Ab, 1024..1087: rwhl (rows 0-7 hi, 8-15 lo).
__global__ __launch_bounds__(256) void k_prep_w(const float* __restrict__ rw,
                                                const float* __restrict__ Am,
                                                const float* __restrict__ Bw,
                                                __bf16* __restrict__ rwhl,
                                                __bf16* __restrict__ Ab,
                                                __bf16* __restrict__ Bwb) {
    const int b = blockIdx.x;
    if (b < 1024) {
        const int o = (b & 511) * 1024 + threadIdx.x * 4;
        const float4 v = *(const float4*)(((b < 512) ? Bw : Am) + o);
        bf16x4 p;
        p[0] = (__bf16)v.x; p[1] = (__bf16)v.y; p[2] = (__bf16)v.z; p[3] = (__bf16)v.w;
        *(bf16x4*)(((b < 512) ? Bwb : Ab) + o) = p;
    } else {
        const int o = (b - 1024) * 1024 + threadIdx.x * 4;   // 0..65535
        const int row = o >> 12, k = o & 4095;
        const float4 v = *(const float4*)(rw + ((size_t)(row & 7) << 12) + k);
        bf16x4 p;
        if (row < 8) {
            p[0] = (__bf16)v.x; p[1] = (__bf16)v.y; p[2] = (__bf16)v.z; p[3] = (__bf16)v.w;
        } else {
            p[0] = (__bf16)(v.x - (float)(__bf16)v.x);
            p[1] = (__bf16)(v.y - (float)(__bf16)v.y);
            p[2] = (__bf16)(v.z - (float)(__bf16)v.z);
            p[3] = (__bf16)(v.w - (float)(__bf16)v.w);
        }
        *(bf16x4*)(rwhl + o) = p;
    }
}

// ---------------- k1: routing -- k_h-style deep-pipelined MFMA ----------------
// 512 blocks x 256 thr (4 waves, launch_bounds(256,1) -> big VGPR budget).
// Block = 16 tokens; wave = K-slice 1024. Grouped-4 prefetch: 12 loads in
// flight, NO barrier in the K-loop. B-frag = rwhl row m (bf16, single b128).
// logit[t][e] = sum over waves of (C[t][e] + C[t][e+8]).
__global__ __launch_bounds__(256, 1) void k_route(const float* __restrict__ x,
                                                  const __bf16* __restrict__ rwhl,
                                                  float* __restrict__ w_arr,
                                                  int*   __restrict__ token_list,
                                                  int*   __restrict__ count,
                                                  int*   __restrict__ nflag,
                                                  int*   __restrict__ flaglist) {
    const int t0   = blockIdx.x * 16;
    const int wv   = threadIdx.x >> 6;        // 0..3
    const int lane = threadIdx.x & 63;
    const int m    = lane & 15;
    const int half = lane >> 4;

    const float*  xrow = x    + (size_t)(t0 + m) * DD;
    const __bf16* wrow = rwhl + (size_t)m * DD;

    f32x4 acc = {0.f, 0.f, 0.f, 0.f};
    const int kbase = wv * 1024;
    for (int g = 0; g < 8; g++) {
        float4 xa[4], xc[4]; bf16x8 wb[4];
        #pragma unroll
        for (int i = 0; i < 4; i++) {
            const int k0 = kbase + (g * 4 + i) * 32 + half * 8;
            xa[i] = *(const float4*)(xrow + k0);
            xc[i] = *(const float4*)(xrow + k0 + 4);
            wb[i] = *(const bf16x8*)(wrow + k0);
        }
        #pragma unroll
        for (int i = 0; i < 4; i++)
            acc = __builtin_amdgcn_mfma_f32_16x16x32_bf16(to_bf16x8(xa[i], xc[i]), wb[i], acc, 0, 0, 0);
    }

    // C layout: row = (lane>>4)*4 + reg (token), col = lane&15 (rwhl row)
    __shared__ float Lred[4][16][17];
    #pragma unroll
    for (int r = 0; r < 4; r++)
        Lred[wv][half * 4 + r][m] = acc[r];
    __syncthreads();

    __shared__ float logitS[16][NE];
    if (threadIdx.x < 128) {
        const int t = threadIdx.x >> 3, ee = threadIdx.x & 7;
        float s = 0.f;
        #pragma unroll
        for (int w = 0; w < 4; w++) s += Lred[w][t][ee] + Lred[w][t][ee + 8];
        logitS[t][ee] = s;
    }
    __syncthreads();

    if (threadIdx.x < 16) {
        const int t = threadIdx.x;
        float best = -1e30f, second = -1e30f; int be = 0;
        #pragma unroll
        for (int e = 0; e < NE; e++) {
            const float s = logitS[t][e];
            if (s > best) { second = best; best = s; be = e; }
            else if (s > second) { second = s; }
        }
        const int tok = t0 + t;
        w_arr[tok] = best;
        if (best - second < TAU) {
            const int p = atomicAdd(nflag, 1);
            if (p < MAXFLAG) flaglist[p] = tok;
        } else {
            const int p = atomicAdd(&count[be], 1);
            token_list[be * NTOK + p] = tok;
        }
    }
}

// ---------------- k1b: exact f64 re-route (original f32 data) ----------------
__global__ __launch_bounds__(256) void k_fix(const float* __restrict__ x,
                                             const float* __restrict__ rw,
                                             float* __restrict__ w_arr,
                                             int*   __restrict__ token_list,
                                             int*   __restrict__ count,
                                             const int* __restrict__ nflag,
                                             const int* __restrict__ flaglist) {
    const int wv   = threadIdx.x >> 6;
    const int lane = threadIdx.x & 63;
    int n = *nflag; if (n > MAXFLAG) n = MAXFLAG;

    for (int idx = blockIdx.x * 4 + wv; idx < n; idx += 512) {
        const int tok = flaglist[idx];
        const float* xp = x + (size_t)tok * DD;
        double acc[NE];
        #pragma unroll
        for (int e = 0; e < NE; e++) acc[e] = 0.0;
        for (int i = 0; i < 16; i++) {
            const int d4 = (i * 64 + lane) * 4;
            const float4 xv = *(const float4*)(xp + d4);
            const double x0 = xv.x, x1 = xv.y, x2 = xv.z, x3 = xv.w;
            #pragma unroll
            for (int e = 0; e < NE; e++) {
                const float4 wv4 = *(const float4*)(rw + (size_t)e * DD + d4);
                acc[e] = fma(x0, (double)wv4.x, acc[e]);
                acc[e] = fma(x1, (double)wv4.y, acc[e]);
                acc[e] = fma(x2, (double)wv4.z, acc[e]);
                acc[e] = fma(x3, (double)wv4.w, acc[e]);
            }
        }
        #pragma unroll
        for (int off = 32; off > 0; off >>= 1)
            #pragma unroll
            for (int e = 0; e < NE; e++)
                acc[e] += __shfl_xor(acc[e], off, 64);
        if (lane == 0) {
            double best = acc[0]; int be = 0;
            #pragma unroll
            for (int e = 1; e < NE; e++) if (acc[e] > best) { best = acc[e]; be = e; }
            w_arr[tok] = (float)best;
            const int pos = atomicAdd(&count[be], 1);
            token_list[be * NTOK + pos] = tok;
        }
    }
}

// ---------------- k2: wh[tok][r] = w * (x . A[e]^T) -- proven 18us shape ----------------
__global__ __launch_bounds__(1024) void k_h(const float* __restrict__ x,
                                            const __bf16* __restrict__ Ab,
                                            const float* __restrict__ w_arr,
                                            const int*   __restrict__ token_list,
                                            const int*   __restrict__ count,
                                            __hip_bfloat16* __restrict__ wh) {
    const int e    = blockIdx.x >> 7;         // 8 experts x 128 slots
    const int g    = blockIdx.x & 127;
    const int cnt  = count[e];
    const int base = g * 32;
    if (base >= cnt) return;

    const int wv   = threadIdx.x >> 6;        // 0..15
    const int lane = threadIdx.x & 63;
    const int m    = lane & 15;
    const int half = lane >> 4;

    const int i0 = base + m,  i1 = base + 16 + m;
    const int tok0 = (i0 < cnt) ? token_list[e * NTOK + i0] : 0;
    const int tok1 = (i1 < cnt) ? token_list[e * NTOK + i1] : 0;
    const float*  xr0  = x  + (size_t)tok0 * DD;
    const float*  xr1  = x  + (size_t)tok1 * DD;
    const __bf16* arow = Ab + ((size_t)e * NR + m) * DD;

    f32x4 acc0 = {0.f,0.f,0.f,0.f}, acc1 = {0.f,0.f,0.f,0.f};
    const int kbase = wv * 256;
    #pragma unroll
    for (int kc = 0; kc < 8; kc++) {
        const int k0 = kbase + kc * 32 + half * 8;
        const bf16x8 bfrag = *(const bf16x8*)(arow + k0);
        const bf16x8 a0 = to_bf16x8(*(const float4*)(xr0 + k0),
                                    *(const float4*)(xr0 + k0 + 4));
        const bf16x8 a1 = to_bf16x8(*(const float4*)(xr1 + k0),
                                    *(const float4*)(xr1 + k0 + 4));
        acc0 = __builtin_amdgcn_mfma_f32_16x16x32_bf16(a0, bfrag, acc0, 0, 0, 0);
        acc1 = __builtin_amdgcn_mfma_f32_16x16x32_bf16(a1, bfrag, acc1, 0, 0, 0);
    }

    __shared__ float lds[16][32][17];
    #pragma unroll
    for (int rr = 0; rr < 4; rr++) {
        lds[wv][half * 4 + rr][m]      = acc0[rr];
        lds[wv][16 + half * 4 + rr][m] = acc1[rr];
    }
    __syncthreads();

    if (threadIdx.x < 512) {
        const int t = threadIdx.x >> 4;
        const int r = threadIdx.x & 15;
        const int i2 = base + t;
        if (i2 < cnt) {
            float s = 0.f;
            #pragma unroll
            for (int w = 0; w < 16; w++) s += lds[w][t][r];
            const int tk = token_list[e * NTOK + i2];
            wh[(size_t)tk * NR + r] = (__hip_bfloat16)(s * w_arr[tk]);
        }
    }
}

// ---------------- k3: out = wh . Bw[e]^T ----------------
// r5 grid (16384 blocks x 256 thr) + grouped-8 B-prefetch + nontemporal stores
// (out never pollutes L3 -> x stays resident for the next replay's k_route).
__global__ __launch_bounds__(256, 1) void k_out(const __bf16* __restrict__ Bwb,
                                                const __hip_bfloat16* __restrict__ wh,
                                                const int*   __restrict__ token_list,
                                                const int*   __restrict__ count,
                                                float* __restrict__ out) {
    const int bx    = blockIdx.x;
    const int chunk = bx & 3;
    const int slot  = (bx >> 2) & 511;
    const int e     = bx >> 11;
    const int cnt   = count[e];
    const int base  = slot * 16;
    if (base >= cnt) return;

    const int wv   = threadIdx.x >> 6;        // 0..3
    const int lane = threadIdx.x & 63;
    const int m    = lane & 15;
    const int half = lane >> 4;

    const int  idx   = base + m;
    const bool valid = idx < cnt;
    const int  tok   = valid ? token_list[e * NTOK + idx] : 0;
    const bf16x8 zf  = zero_frag();

    const bf16x8 a2 = (half < 2 && valid)
        ? *(const bf16x8*)((const __bf16*)wh + (size_t)tok * NR + half * 8)
        : zf;

    int trow[4]; bool vrow[4];
    #pragma unroll
    for (int r = 0; r < 4; r++) {
        const int ir = base + half * 4 + r;
        vrow[r] = ir < cnt;
        trow[r] = vrow[r] ? token_list[e * NTOK + ir] : 0;
    }

    const __bf16* bwe = Bwb + (size_t)e * NDO * NR;
    const int h2 = (half < 2) ? half : 0;
    const f32x4 zero4 = {0.f, 0.f, 0.f, 0.f};
    const int ob0 = chunk * 1024 + wv * 256;

    for (int g = 0; g < 2; g++) {
        bf16x8 B[8];
        #pragma unroll
        for (int i = 0; i < 8; i++) {
            const int obase = ob0 + (g * 8 + i) * 16;
            B[i] = (half < 2)
                ? *(const bf16x8*)(bwe + (size_t)(obase + m) * NR + h2 * 8)
                : zf;
        }
        #pragma unroll
        for (int i = 0; i < 8; i++) {
            const int obase = ob0 + (g * 8 + i) * 16;
            const f32x4 d = __builtin_amdgcn_mfma_f32_16x16x32_bf16(a2, B[i], zero4, 0, 0, 0);
            #pragma unroll
            for (int r = 0; r < 4; r++) {
                if (vrow[r])
                    __builtin_nontemporal_store(d[r], &out[(size_t)trow[r] * NDO + obase + m]);
            }
        }
    }
}

// ---------------- launcher ----------------
extern "C" void kernel_launch(void* const* d_in, const int* in_sizes, int n_in,
                              void* d_out, int out_size, void* d_ws, size_t ws_size,
                              hipStream_t stream) {
    const float* x  = (const float*)d_in[0];
    const float* rw = (const float*)d_in[1];
    const float* Am = (const float*)d_in[2];
    const float* Bw = (const float*)d_in[3];
    float* out = (float*)d_out;

    char* ws = (char*)d_ws;
    int*   count      = (int*)ws;                           // 8 ints @ 0
    int*   nflag      = (int*)(ws + 32);                    // 1 int
    float* w_arr      = (float*)(ws + 512);                 // 8192 f32   -> ends 33280
    int*   flaglist   = (int*)(ws + 33280);                 // 8000 ints  -> ends 65280
    int*   token_list = (int*)(ws + 65536);                 // 64K ints   -> ends 327680
    __hip_bfloat16* wh = (__hip_bfloat16*)(ws + 327680);    // 128K bf16  -> ends 589824
    __bf16* rwhl      = (__bf16*)(ws + 589824);             // 64K bf16   -> ends 720896
    __bf16* Bwb       = (__bf16*)(ws + 720896);             // 512K bf16  -> ends 1769472
    __bf16* Ab        = (__bf16*)(ws + 1769472);            // 512K bf16  -> ends 2818048

    hipMemsetAsync(ws, 0, 64, stream);                      // count + nflag
    hipLaunchKernelGGL(k_prep_w, dim3(1088),  dim3(256),  0, stream, rw, Am, Bw, rwhl, Ab, Bwb);
    hipLaunchKernelGGL(k_route,  dim3(512),   dim3(256),  0, stream, x, rwhl, w_arr, token_list, count, nflag, flaglist);
    hipLaunchKernelGGL(k_fix,    dim3(128),   dim3(256),  0, stream, x, rw, w_arr, token_list, count, nflag, flaglist);
    hipLaunchKernelGGL(k_h,      dim3(1024),  dim3(1024), 0, stream, x, Ab, w_arr, token_list, count, wh);
    hipLaunchKernelGGL(k_out,    dim3(16384), dim3(256),  0, stream, Bwb, wh, token_list, count, out);
}

// Round 12
// 149.188 us; speedup vs baseline: 1.2238x; 1.0797x over previous
//
#include <hip/hip_runtime.h>
#include <hip/hip_bf16.h>

#define DD   4096   // hidden dim
#define NE   8      // experts
#define NR   16     // lora rank
#define NTOK 8192   // B*S
#define NDO  4096   // output dim
#define TAU  0.01f  // ambiguity margin (bf16-x routing err, r9-r11-validated)
#define MAXFLAG 8000
// SCALING = 16/16 = 1.0

typedef __attribute__((ext_vector_type(8))) __bf16 bf16x8;
typedef __attribute__((ext_vector_type(4))) __bf16 bf16x4;
typedef __attribute__((ext_vector_type(4))) float  f32x4;

__device__ __forceinline__ bf16x8 to_bf16x8(float4 a, float4 b) {
    bf16x8 r;
    r[0] = (__bf16)a.x; r[1] = (__bf16)a.y; r[2] = (__bf16)a.z; r[3] = (__bf16)a.w;
    r[4] = (__bf16)b.x; r[5] = (__bf16)b.y; r[6] = (__bf16)b.z; r[7] = (__bf16)b.w;
    return r;
}

__device__ __forceinline__ bf16x8 zero_frag() {
    bf16x8 z;
    #pragma unroll
    for (int j = 0; j < 8; j++) z[j] = (__bf16)0.0f;
    return z;
}

// ---------------- k_prep_w: weight conversions (tiny, ~2.2MB total) ----------------
// blocks 0..511: Bwb, 512..1023: Ab, 1024..1087: rwhl (rows 0-7 hi, 8-15 lo).
__global__ __launch_bounds__(256) void k_prep_w(const float* __restrict__ rw,
                                                const float* __restrict__ Am,
                                                const float* __restrict__ Bw,
                                                __bf16* __restrict__ rwhl,
                                                __bf16* __restrict__ Ab,
                                                __bf16* __restrict__ Bwb) {
    const int b = blockIdx.x;
    if (b < 1024) {
        const int o = (b & 511) * 1024 + threadIdx.x * 4;
        const float4 v = *(const float4*)(((b < 512) ? Bw : Am) + o);
        bf16x4 p;
        p[0] = (__bf16)v.x; p[1] = (__bf16)v.y; p[2] = (__bf16)v.z; p[3] = (__bf16)v.w;
        *(bf16x4*)(((b < 512) ? Bwb : Ab) + o) = p;
    } else {
        const int o = (b - 1024) * 1024 + threadIdx.x * 4;   // 0..65535
        const int row = o >> 12, k = o & 4095;
        const float4 v = *(const float4*)(rw + ((size_t)(row & 7) << 12) + k);
        bf16x4 p;
        if (row < 8) {
            p[0] = (__bf16)v.x; p[1] = (__bf16)v.y; p[2] = (__bf16)v.z; p[3] = (__bf16)v.w;
        } else {
            p[0] = (__bf16)(v.x - (float)(__bf16)v.x);
            p[1] = (__bf16)(v.y - (float)(__bf16)v.y);
            p[2] = (__bf16)(v.z - (float)(__bf16)v.z);
            p[3] = (__bf16)(v.w - (float)(__bf16)v.w);
        }
        *(bf16x4*)(rwhl + o) = p;
    }
}

// ---------------- k1a: routing partials -- 8192 waves, NO barriers in K-loop ----------------
// 2048 blocks x 256 thr (4 waves). Block = 16 tokens x K-quarter(1024);
// wave = K-slice 256. Deterministic: partial logits to pbuf[kg][tok][e].
__global__ __launch_bounds__(256, 1) void k_route_part(const float* __restrict__ x,
                                                       const __bf16* __restrict__ rwhl,
                                                       float* __restrict__ pbuf) {
    const int tg = blockIdx.x >> 2;           // token group (16 tokens)
    const int kg = blockIdx.x & 3;            // K-quarter
    const int t0 = tg * 16;
    const int wv = threadIdx.x >> 6;          // 0..3
    const int lane = threadIdx.x & 63;
    const int m = lane & 15;
    const int half = lane >> 4;

    const float*  xrow = x    + (size_t)(t0 + m) * DD;
    const __bf16* wrow = rwhl + (size_t)m * DD;

    f32x4 acc = {0.f, 0.f, 0.f, 0.f};
    const int kbase = kg * 1024 + wv * 256;
    #pragma unroll
    for (int ks = 0; ks < 8; ks++) {
        const int k0 = kbase + ks * 32 + half * 8;
        const float4 xa = *(const float4*)(xrow + k0);
        const float4 xc = *(const float4*)(xrow + k0 + 4);
        const bf16x8 wb = *(const bf16x8*)(wrow + k0);
        acc = __builtin_amdgcn_mfma_f32_16x16x32_bf16(to_bf16x8(xa, xc), wb, acc, 0, 0, 0);
    }

    // C layout: row = (lane>>4)*4 + reg (token), col = lane&15 (rwhl row)
    __shared__ float Lred[4][16][17];
    #pragma unroll
    for (int r = 0; r < 4; r++)
        Lred[wv][half * 4 + r][m] = acc[r];
    __syncthreads();

    if (threadIdx.x < 128) {
        const int t = threadIdx.x >> 3, ee = threadIdx.x & 7;
        float s = 0.f;
        #pragma unroll
        for (int w = 0; w < 4; w++) s += Lred[w][t][ee] + Lred[w][t][ee + 8];
        pbuf[((size_t)kg * NTOK + t0 + t) * NE + ee] = s;
    }
}

// ---------------- k1b: finalize -- argmax + TAU flag + binning ----------------
// 32 blocks x 256 thr; thread = token. Reads 4 kg-partials (coalesced 32B).
__global__ __launch_bounds__(256) void k_route_fin(const float* __restrict__ pbuf,
                                                   float* __restrict__ w_arr,
                                                   int*   __restrict__ token_list,
                                                   int*   __restrict__ count,
                                                   int*   __restrict__ nflag,
                                                   int*   __restrict__ flaglist) {
    const int tok = blockIdx.x * 256 + threadIdx.x;
    float l[NE];
    #pragma unroll
    for (int e = 0; e < NE; e++)
        l[e] = pbuf[((size_t)0 * NTOK + tok) * NE + e]
             + pbuf[((size_t)1 * NTOK + tok) * NE + e]
             + pbuf[((size_t)2 * NTOK + tok) * NE + e]
             + pbuf[((size_t)3 * NTOK + tok) * NE + e];

    float best = -1e30f, second = -1e30f; int be = 0;
    #pragma unroll
    for (int e = 0; e < NE; e++) {
        if (l[e] > best) { second = best; best = l[e]; be = e; }
        else if (l[e] > second) { second = l[e]; }
    }
    w_arr[tok] = best;
    if (best - second < TAU) {
        const int p = atomicAdd(nflag, 1);
        if (p < MAXFLAG) flaglist[p] = tok;
    } else {
        const int p = atomicAdd(&count[be], 1);
        token_list[be * NTOK + p] = tok;
    }
}

// ---------------- k1c: exact f64 re-route (original f32 data) ----------------
__global__ __launch_bounds__(256) void k_fix(const float* __restrict__ x,
                                             const float* __restrict__ rw,
                                             float* __restrict__ w_arr,
                                             int*   __restrict__ token_list,
                                             int*   __restrict__ count,
                                             const int* __restrict__ nflag,
                                             const int* __restrict__ flaglist) {
    const int wv   = threadIdx.x >> 6;
    const int lane = threadIdx.x & 63;
    int n = *nflag; if (n > MAXFLAG) n = MAXFLAG;

    for (int idx = blockIdx.x * 4 + wv; idx < n; idx += 512) {
        const int tok = flaglist[idx];
        const float* xp = x + (size_t)tok * DD;
        double acc[NE];
        #pragma unroll
        for (int e = 0; e < NE; e++) acc[e] = 0.0;
        for (int i = 0; i < 16; i++) {
            const int d4 = (i * 64 + lane) * 4;
            const float4 xv = *(const float4*)(xp + d4);
            const double x0 = xv.x, x1 = xv.y, x2 = xv.z, x3 = xv.w;
            #pragma unroll
            for (int e = 0; e < NE; e++) {
                const float4 wv4 = *(const float4*)(rw + (size_t)e * DD + d4);
                acc[e] = fma(x0, (double)wv4.x, acc[e]);
                acc[e] = fma(x1, (double)wv4.y, acc[e]);
                acc[e] = fma(x2, (double)wv4.z, acc[e]);
                acc[e] = fma(x3, (double)wv4.w, acc[e]);
            }
        }
        #pragma unroll
        for (int off = 32; off > 0; off >>= 1)
            #pragma unroll
            for (int e = 0; e < NE; e++)
                acc[e] += __shfl_xor(acc[e], off, 64);
        if (lane == 0) {
            double best = acc[0]; int be = 0;
            #pragma unroll
            for (int e = 1; e < NE; e++) if (acc[e] > best) { best = acc[e]; be = e; }
            w_arr[tok] = (float)best;
            const int pos = atomicAdd(&count[be], 1);
            token_list[be * NTOK + pos] = tok;
        }
    }
}

// ---------------- k2: wh[tok][r] = w * (x . A[e]^T) -- proven shape ----------------
__global__ __launch_bounds__(1024) void k_h(const float* __restrict__ x,
                                            const __bf16* __restrict__ Ab,
                                            const float* __restrict__ w_arr,
                                            const int*   __restrict__ token_list,
                                            const int*   __restrict__ count,
                                            __hip_bfloat16* __restrict__ wh) {
    const int e    = blockIdx.x >> 7;         // 8 experts x 128 slots
    const int g    = blockIdx.x & 127;
    const int cnt  = count[e];
    const int base = g * 32;
    if (base >= cnt) return;

    const int wv   = threadIdx.x >> 6;        // 0..15
    const int lane = threadIdx.x & 63;
    const int m    = lane & 15;
    const int half = lane >> 4;

    const int i0 = base + m,  i1 = base + 16 + m;
    const int tok0 = (i0 < cnt) ? token_list[e * NTOK + i0] : 0;
    const int tok1 = (i1 < cnt) ? token_list[e * NTOK + i1] : 0;
    const float*  xr0  = x  + (size_t)tok0 * DD;
    const float*  xr1  = x  + (size_t)tok1 * DD;
    const __bf16* arow = Ab + ((size_t)e * NR + m) * DD;

    f32x4 acc0 = {0.f,0.f,0.f,0.f}, acc1 = {0.f,0.f,0.f,0.f};
    const int kbase = wv * 256;
    #pragma unroll
    for (int kc = 0; kc < 8; kc++) {
        const int k0 = kbase + kc * 32 + half * 8;
        const bf16x8 bfrag = *(const bf16x8*)(arow + k0);
        const bf16x8 a0 = to_bf16x8(*(const float4*)(xr0 + k0),
                                    *(const float4*)(xr0 + k0 + 4));
        const bf16x8 a1 = to_bf16x8(*(const float4*)(xr1 + k0),
                                    *(const float4*)(xr1 + k0 + 4));
        acc0 = __builtin_amdgcn_mfma_f32_16x16x32_bf16(a0, bfrag, acc0, 0, 0, 0);
        acc1 = __builtin_amdgcn_mfma_f32_16x16x32_bf16(a1, bfrag, acc1, 0, 0, 0);
    }

    __shared__ float lds[16][32][17];
    #pragma unroll
    for (int rr = 0; rr < 4; rr++) {
        lds[wv][half * 4 + rr][m]      = acc0[rr];
        lds[wv][16 + half * 4 + rr][m] = acc1[rr];
    }
    __syncthreads();

    if (threadIdx.x < 512) {
        const int t = threadIdx.x >> 4;
        const int r = threadIdx.x & 15;
        const int i2 = base + t;
        if (i2 < cnt) {
            float s = 0.f;
            #pragma unroll
            for (int w = 0; w < 16; w++) s += lds[w][t][r];
            const int tk = token_list[e * NTOK + i2];
            wh[(size_t)tk * NR + r] = (__hip_bfloat16)(s * w_arr[tk]);
        }
    }
}

// ---------------- k3: out = wh . Bw[e]^T + LDS-transpose epilogue ----------------
// 16384 blocks x 256 thr. Block = 16 tokens x 1024-o chunk. MFMA results land
// in a [16][1024] LDS tile; epilogue stores 16 rounds of 256-lane float4 =
// 4KB CONTIGUOUS nontemporal stores per row (fill-like write pattern).
__global__ __launch_bounds__(256, 1) void k_out(const __bf16* __restrict__ Bwb,
                                                const __hip_bfloat16* __restrict__ wh,
                                                const int*   __restrict__ token_list,
                                                const int*   __restrict__ count,
                                                float* __restrict__ out) {
    const int bx    = blockIdx.x;
    const int chunk = bx & 3;
    const int slot  = (bx >> 2) & 511;
    const int e     = bx >> 11;
    const int cnt   = count[e];
    const int base  = slot * 16;
    if (base >= cnt) return;

    const int wv   = threadIdx.x >> 6;        // 0..3
    const int lane = threadIdx.x & 63;
    const int m    = lane & 15;
    const int half = lane >> 4;

    const int  idx   = base + m;
    const bool valid = idx < cnt;
    const int  tok   = valid ? token_list[e * NTOK + idx] : 0;
    const bf16x8 zf  = zero_frag();

    const bf16x8 a2 = (half < 2 && valid)
        ? *(const bf16x8*)((const __bf16*)wh + (size_t)tok * NR + half * 8)
        : zf;

    __shared__ float lds[16][1028];           // +4 pad: MFMA writes 2-way (free)
    const __bf16* bwe = Bwb + (size_t)e * NDO * NR;
    const int h2 = (half < 2) ? half : 0;
    const f32x4 zero4 = {0.f, 0.f, 0.f, 0.f};
    const int ob0 = wv * 256;                 // col within the block's 1024 chunk

    for (int g = 0; g < 2; g++) {
        bf16x8 B[8];
        #pragma unroll
        for (int i = 0; i < 8; i++) {
            const int oc = chunk * 1024 + ob0 + (g * 8 + i) * 16;
            B[i] = (half < 2)
                ? *(const bf16x8*)(bwe + (size_t)(oc + m) * NR + h2 * 8)
                : zf;
        }
        #pragma unroll
        for (int i = 0; i < 8; i++) {
            const f32x4 d = __builtin_amdgcn_mfma_f32_16x16x32_bf16(a2, B[i], zero4, 0, 0, 0);
            const int col = ob0 + (g * 8 + i) * 16 + m;
            #pragma unroll
            for (int r = 0; r < 4; r++)
                lds[half * 4 + r][col] = d[r];
        }
    }
    __syncthreads();

    // epilogue: one output row per round, 256 lanes x float4 = 4KB contiguous
    #pragma unroll 4
    for (int r = 0; r < 16; r++) {
        const int ir = base + r;
        if (ir < cnt) {
            const int tr = token_list[e * NTOK + ir];
            const float4 v = *(const float4*)&lds[r][threadIdx.x * 4];
            float* dst = out + (size_t)tr * NDO + chunk * 1024 + threadIdx.x * 4;
            __builtin_nontemporal_store(v.x, dst + 0);
            __builtin_nontemporal_store(v.y, dst + 1);
            __builtin_nontemporal_store(v.z, dst + 2);
            __builtin_nontemporal_store(v.w, dst + 3);
        }
    }
}

// ---------------- launcher ----------------
extern "C" void kernel_launch(void* const* d_in, const int* in_sizes, int n_in,
                              void* d_out, int out_size, void* d_ws, size_t ws_size,
                              hipStream_t stream) {
    const float* x  = (const float*)d_in[0];
    const float* rw = (const float*)d_in[1];
    const float* Am = (const float*)d_in[2];
    const float* Bw = (const float*)d_in[3];
    float* out = (float*)d_out;

    char* ws = (char*)d_ws;
    int*   count      = (int*)ws;                           // 8 ints @ 0
    int*   nflag      = (int*)(ws + 32);                    // 1 int
    float* w_arr      = (float*)(ws + 512);                 // 8192 f32   -> ends 33280
    int*   flaglist   = (int*)(ws + 33280);                 // 8000 ints  -> ends 65280
    int*   token_list = (int*)(ws + 65536);                 // 64K ints   -> ends 327680
    __hip_bfloat16* wh = (__hip_bfloat16*)(ws + 327680);    // 128K bf16  -> ends 589824
    __bf16* rwhl      = (__bf16*)(ws + 589824);             // 64K bf16   -> ends 720896
    __bf16* Bwb       = (__bf16*)(ws + 720896);             // 512K bf16  -> ends 1769472
    __bf16* Ab        = (__bf16*)(ws + 1769472);            // 512K bf16  -> ends 2818048
    float*  pbuf      = (float*)(ws + 3145728);             // 4*8192*8 f32 = 1MB -> ends 4194304

    hipMemsetAsync(ws, 0, 64, stream);                      // count + nflag
    hipLaunchKernelGGL(k_prep_w,     dim3(1088),  dim3(256), 0, stream, rw, Am, Bw, rwhl, Ab, Bwb);
    hipLaunchKernelGGL(k_route_part, dim3(2048),  dim3(256), 0, stream, x, rwhl, pbuf);
    hipLaunchKernelGGL(k_route_fin,  dim3(32),    dim3(256), 0, stream, pbuf, w_arr, token_list, count, nflag, flaglist);
    hipLaunchKernelGGL(k_fix,        dim3(128),   dim3(256), 0, stream, x, rw, w_arr, token_list, count, nflag, flaglist);
    hipLaunchKernelGGL(k_h,          dim3(1024),  dim3(1024),0, stream, x, Ab, w_arr, token_list, count, wh);
    hipLaunchKernelGGL(k_out,        dim3(16384), dim3(256), 0, stream, Bwb, wh, token_list, count, out);
}